// Round 4
// baseline (766.477 us; speedup 1.0000x reference)
//
#include <hip/hip_runtime.h>

#define N_NODES 50000
#define N_EDGES 800000
#define IN_DIM 128
#define OUT_DIM 64

#define GROUP_ROWS 64
#define GEMM_BLOCKS 782               // ceil(50000/64)

typedef _Float16 h2 __attribute__((ext_vector_type(2)));
typedef _Float16 h4 __attribute__((ext_vector_type(4)));
typedef _Float16 h8 __attribute__((ext_vector_type(8)));
typedef float    f4 __attribute__((ext_vector_type(4)));

#define LDK 136    // padded fp16 K-stride (multiple of 8 -> 16B-aligned b128 rows)

// ---------------------------------------------------------------------------
// K1: MFMA fp16 GEMM per 64-row group (proven code) + zero this group's out
// rows (folds the memset dispatch away; K2's atomics accumulate into out).
// ---------------------------------------------------------------------------
__global__ __launch_bounds__(256) void gemm_support(const float* __restrict__ x,
                                                    const float* __restrict__ w,
                                                    _Float16* __restrict__ support,
                                                    float* __restrict__ out) {
    __shared__ char smem[GROUP_ROWS * LDK * 2 + OUT_DIM * LDK * 2];  // 34816 B
    const int tid = threadIdx.x;
    const int rowbase = blockIdx.x * GROUP_ROWS;

    // zero out rows for this group: 64 rows x 16 float4 = 1024 float4
    {
        const float4 z = make_float4(0.f, 0.f, 0.f, 0.f);
        #pragma unroll
        for (int i = tid; i < GROUP_ROWS * (OUT_DIM / 4); i += 256) {
            int r = rowbase + (i >> 4);
            if (r < N_NODES) *(float4*)&out[(size_t)r * OUT_DIM + (i & 15) * 4] = z;
        }
    }

    _Float16* xb = (_Float16*)smem;                          // [64][LDK]
    _Float16* wt = (_Float16*)(smem + GROUP_ROWS * LDK * 2); // [64][LDK], wt[n][k]

    // conflict-free wt staging (register transpose, fp16-pair stores)
    {
        const int n_s = tid >> 2;         // 0..63
        const int kp0 = tid & 3;
        #pragma unroll
        for (int it = 0; it < 16; ++it) {
            int kp = kp0 + (it << 2);     // k-pair index 0..63
            int k  = kp << 1;
            h2 hv = { (_Float16)w[(size_t)k * OUT_DIM + n_s],
                      (_Float16)w[(size_t)(k + 1) * OUT_DIM + n_s] };
            *(h2*)&wt[n_s * LDK + k] = hv;
        }
    }
    for (int i = tid; i < GROUP_ROWS * (IN_DIM / 4); i += 256) {
        int r  = i >> 5;
        int kq = i & 31;
        int row = rowbase + r;
        float4 v = (row < N_NODES)
                       ? *(const float4*)&x[(size_t)row * IN_DIM + kq * 4]
                       : make_float4(0.f, 0.f, 0.f, 0.f);
        h4 hv = { (_Float16)v.x, (_Float16)v.y, (_Float16)v.z, (_Float16)v.w };
        *(h4*)&xb[r * LDK + kq * 4] = hv;
    }
    __syncthreads();

    const int wave = tid >> 6;
    const int lane = tid & 63;
    const int mrow = lane & 15;
    const int quad = lane >> 4;
    const int m0   = wave * 16;

    f4 acc[4];
    #pragma unroll
    for (int t = 0; t < 4; ++t) acc[t] = (f4){0.f, 0.f, 0.f, 0.f};

    #pragma unroll
    for (int ks = 0; ks < 4; ++ks) {
        int kof = ks * 32 + quad * 8;
        h8 a = *(h8*)&xb[(m0 + mrow) * LDK + kof];
        #pragma unroll
        for (int t = 0; t < 4; ++t) {
            h8 b = *(h8*)&wt[(t * 16 + mrow) * LDK + kof];
            acc[t] = __builtin_amdgcn_mfma_f32_16x16x32_f16(a, b, acc[t], 0, 0, 0);
        }
    }

    #pragma unroll
    for (int t = 0; t < 4; ++t) {
        #pragma unroll
        for (int r = 0; r < 4; ++r) {
            int row = rowbase + m0 + quad * 4 + r;
            if (row < N_NODES)
                support[(size_t)row * OUT_DIM + t * 16 + mrow] = (_Float16)acc[t][r];
        }
    }
}

// ---------------------------------------------------------------------------
// K2: segment_sum as fire-and-forget f32 atomic scatter.  16 lanes per edge
// (lane g owns 4 output columns): broadcast edge triple, coalesced 128B
// support-row gather (L2/L3-resident), 4 atomicAdd into out.  No returns ->
// no dependency stalls; 50000 blocks give massive TLP to hide gather latency.
// ---------------------------------------------------------------------------
__global__ __launch_bounds__(256) void scatter_edges(const int* __restrict__ erow,
                                                     const int* __restrict__ ecol,
                                                     const float* __restrict__ ev,
                                                     const _Float16* __restrict__ support,
                                                     float* __restrict__ out) {
    const int tid = threadIdx.x;
    const int e   = blockIdx.x * 16 + (tid >> 4);   // 50000 * 16 == 800000 exactly
    const int g   = tid & 15;

    int   r = erow[e];
    int   c = ecol[e];
    float v = ev[e];
    h4 s = *(const h4*)&support[(size_t)c * OUT_DIM + g * 4];
    float* o = &out[(size_t)r * OUT_DIM + g * 4];
    atomicAdd(o + 0, v * (float)s[0]);
    atomicAdd(o + 1, v * (float)s[1]);
    atomicAdd(o + 2, v * (float)s[2]);
    atomicAdd(o + 3, v * (float)s[3]);
}

// ---------------------------------------------------------------------------
// K3: in-place fused ReLU over out (3.2M floats as 800K float4).
// ---------------------------------------------------------------------------
__global__ __launch_bounds__(256) void relu_out(float* __restrict__ out) {
    const int i = blockIdx.x * 256 + threadIdx.x;   // 3125 * 256 == 800000 float4
    float4* p = (float4*)out;
    float4 a = p[i];
    a.x = fmaxf(a.x, 0.f);
    a.y = fmaxf(a.y, 0.f);
    a.z = fmaxf(a.z, 0.f);
    a.w = fmaxf(a.w, 0.f);
    p[i] = a;
}

extern "C" void kernel_launch(void* const* d_in, const int* in_sizes, int n_in,
                              void* d_out, int out_size, void* d_ws, size_t ws_size,
                              hipStream_t stream) {
    const float* x    = (const float*)d_in[0];
    const int*   erow = (const int*)  d_in[1];
    const int*   ecol = (const int*)  d_in[2];
    const float* ev   = (const float*)d_in[3];
    const float* w    = (const float*)d_in[4];
    float* out = (float*)d_out;

    // workspace: only the fp16 support matrix (6.4 MB of the 256 MiB ws)
    _Float16* support = (_Float16*)d_ws;

    gemm_support<<<GEMM_BLOCKS, 256, 0, stream>>>(x, w, support, out);
    scatter_edges<<<N_EDGES / 16, 256, 0, stream>>>(erow, ecol, ev, support, out);
    relu_out<<<(N_NODES * OUT_DIM) / (4 * 256), 256, 0, stream>>>(out);
}

// Round 5
// 128.043 us; speedup vs baseline: 5.9861x; 5.9861x over previous
//
#include <hip/hip_runtime.h>

#define N_NODES 50000
#define N_EDGES 800000
#define IN_DIM 128
#define OUT_DIM 64

#define GROUP_SHIFT 6                 // 64 rows per group
#define GROUP_ROWS 64
#define N_GROUPS 782                  // ceil(50000/64)
#define SLAB 1216                     // slab capacity per group (mean 1024, +6 sigma)
#define CHUNK2 2048                   // edges per fill block
#define FILL_BLOCKS 391               // 391*2048 >= 800000 (fill role on blocks 0..390)
#define QBITS 2                       // col quartiles for L2-resident gather phasing
#define NBINS (GROUP_ROWS << QBITS)   // 256 sort bins: (row<<2) | col_quartile
#define QSTEP 12500                   // N_NODES/4

typedef _Float16 h2 __attribute__((ext_vector_type(2)));
typedef _Float16 h4 __attribute__((ext_vector_type(4)));
typedef _Float16 h8 __attribute__((ext_vector_type(8)));
typedef float    f4 __attribute__((ext_vector_type(4)));

#define LDK 136    // padded fp16 K-stride (multiple of 8 -> 16B-aligned b128 rows)

// ---------------------------------------------------------------------------
// D1 (fused, byte-identical to the proven 124.3us version): blocks [0,391) =
// fill role; blocks [391,1173) = MFMA fp16 GEMM per 64-row group.
// ---------------------------------------------------------------------------
__global__ __launch_bounds__(256) void fused_gemm_fill(const float* __restrict__ x,
                                                       const float* __restrict__ w,
                                                       const int* __restrict__ erow,
                                                       const int* __restrict__ ecol,
                                                       const float* __restrict__ eval,
                                                       _Float16* __restrict__ support,
                                                       int* __restrict__ gcursor,
                                                       int2* __restrict__ bucket) {
    __shared__ char smem[GROUP_ROWS * LDK * 2 + OUT_DIM * LDK * 2];  // 34816 B
    const int tid = threadIdx.x;

    if (blockIdx.x >= FILL_BLOCKS) {
        // ---- GEMM role (blocks 391..1172, group = blockIdx-391) ----
        _Float16* xb = (_Float16*)smem;                          // [64][LDK]
        _Float16* wt = (_Float16*)(smem + GROUP_ROWS * LDK * 2); // [64][LDK], wt[n][k]

        // conflict-free wt staging (register transpose, fp16-pair stores)
        {
            const int n_s = tid >> 2;         // 0..63
            const int kp0 = tid & 3;
            #pragma unroll
            for (int it = 0; it < 16; ++it) {
                int kp = kp0 + (it << 2);     // k-pair index 0..63
                int k  = kp << 1;
                h2 hv = { (_Float16)w[(size_t)k * OUT_DIM + n_s],
                          (_Float16)w[(size_t)(k + 1) * OUT_DIM + n_s] };
                *(h2*)&wt[n_s * LDK + k] = hv;
            }
        }
        const int rowbase = (blockIdx.x - FILL_BLOCKS) * GROUP_ROWS;
        for (int i = tid; i < GROUP_ROWS * (IN_DIM / 4); i += 256) {
            int r  = i >> 5;
            int kq = i & 31;
            int row = rowbase + r;
            float4 v = (row < N_NODES)
                           ? *(const float4*)&x[(size_t)row * IN_DIM + kq * 4]
                           : make_float4(0.f, 0.f, 0.f, 0.f);
            h4 hv = { (_Float16)v.x, (_Float16)v.y, (_Float16)v.z, (_Float16)v.w };
            *(h4*)&xb[r * LDK + kq * 4] = hv;
        }
        __syncthreads();

        const int wave = tid >> 6;
        const int lane = tid & 63;
        const int mrow = lane & 15;
        const int quad = lane >> 4;
        const int m0   = wave * 16;

        f4 acc[4];
        #pragma unroll
        for (int t = 0; t < 4; ++t) acc[t] = (f4){0.f, 0.f, 0.f, 0.f};

        #pragma unroll
        for (int ks = 0; ks < 4; ++ks) {
            int kof = ks * 32 + quad * 8;
            h8 a = *(h8*)&xb[(m0 + mrow) * LDK + kof];
            #pragma unroll
            for (int t = 0; t < 4; ++t) {
                h8 b = *(h8*)&wt[(t * 16 + mrow) * LDK + kof];
                acc[t] = __builtin_amdgcn_mfma_f32_16x16x32_f16(a, b, acc[t], 0, 0, 0);
            }
        }

        #pragma unroll
        for (int t = 0; t < 4; ++t) {
            #pragma unroll
            for (int r = 0; r < 4; ++r) {
                int row = rowbase + m0 + quad * 4 + r;
                if (row < N_NODES)
                    support[(size_t)row * OUT_DIM + t * 16 + mrow] = (_Float16)acc[t][r];
            }
        }
    } else {
        // ---- fill role (blocks 0..390) ----
        int* lcnt  = (int*)smem;
        int* lbase = lcnt + N_GROUPS;
        for (int i = tid; i < N_GROUPS; i += 256) lcnt[i] = 0;
        __syncthreads();
        const int base = blockIdx.x * CHUNK2;
        #pragma unroll 4
        for (int i = 0; i < CHUNK2 / 256; ++i) {
            int e = base + tid + i * 256;
            if (e < N_EDGES) atomicAdd(&lcnt[erow[e] >> GROUP_SHIFT], 1);
        }
        __syncthreads();
        for (int i = tid; i < N_GROUPS; i += 256) {
            int c = lcnt[i];
            lbase[i] = c ? atomicAdd(&gcursor[i], c) : 0;
            lcnt[i]  = 0;
        }
        __syncthreads();
        #pragma unroll 4
        for (int i = 0; i < CHUNK2 / 256; ++i) {
            int e = base + tid + i * 256;
            if (e < N_EDGES) {
                int r = erow[e];
                int g = r >> GROUP_SHIFT;
                int p = atomicAdd(&lcnt[g], 1);
                bucket[(size_t)g * SLAB + lbase[g] + p] =
                    make_int2(((r & (GROUP_ROWS - 1)) << 16) | ecol[e],
                              __float_as_int(eval[e]));
            }
        }
    }
}

// ---------------------------------------------------------------------------
// D2: one 1024-thread block per 64-row group.  Counting sort by
// (row, col_quartile) -> 256 bins: per-row ranges stay contiguous, but every
// thread walks low support columns first, so chip-wide the gather's working
// set is one 1.6MB quarter of support at a time -> fits each XCD's 4MiB L2
// (6.4MB did not -> L3 random-line bound).  Gather unrolled x4, fused ReLU.
// ---------------------------------------------------------------------------
__global__ __launch_bounds__(1024) void reduce_group(const int* __restrict__ gcursor,
                                                     const int2* __restrict__ bucket,
                                                     const _Float16* __restrict__ support,
                                                     float* __restrict__ out) {
    __shared__ int2 ebuf[SLAB];
    __shared__ int2 ebuf2[SLAB];
    __shared__ int  rcnt[NBINS];
    __shared__ int  rstart[NBINS + 1];
    __shared__ int  rcur[NBINS];
    const int grp = blockIdx.x;
    const int cnt = min(gcursor[grp], SLAB);
    const size_t sb = (size_t)grp * SLAB;
    const int tid = threadIdx.x;

    if (tid < NBINS) rcnt[tid] = 0;
    __syncthreads();
    for (int j = tid; j < cnt; j += 1024) {
        int2 cv = bucket[sb + j];
        ebuf[j] = cv;
        int c = cv.x & 0xFFFF;
        int q = (c >= QSTEP) + (c >= 2 * QSTEP) + (c >= 3 * QSTEP);
        atomicAdd(&rcnt[((cv.x >> 16) << QBITS) | q], 1);
    }
    __syncthreads();
    // one-wave exclusive scan over 256 bins (4 bins per lane)
    if (tid < 64) {
        int b0 = rcnt[tid * 4 + 0];
        int b1 = rcnt[tid * 4 + 1];
        int b2 = rcnt[tid * 4 + 2];
        int b3 = rcnt[tid * 4 + 3];
        int loc = b0 + b1 + b2 + b3;
        int incl = loc;
        #pragma unroll
        for (int off = 1; off < 64; off <<= 1) {
            int t = __shfl_up(incl, off, 64);
            if (tid >= off) incl += t;
        }
        int ex = incl - loc;
        rstart[tid * 4 + 0] = ex;           rcur[tid * 4 + 0] = ex;
        rstart[tid * 4 + 1] = ex + b0;      rcur[tid * 4 + 1] = ex + b0;
        rstart[tid * 4 + 2] = ex + b0 + b1; rcur[tid * 4 + 2] = ex + b0 + b1;
        rstart[tid * 4 + 3] = ex + b0 + b1 + b2;
        rcur[tid * 4 + 3]   = ex + b0 + b1 + b2;
        if (tid == 63) rstart[NBINS] = incl;
    }
    __syncthreads();
    for (int j = tid; j < cnt; j += 1024) {
        int2 cv = ebuf[j];
        int c = cv.x & 0xFFFF;
        int q = (c >= QSTEP) + (c >= 2 * QSTEP) + (c >= 3 * QSTEP);
        int p = atomicAdd(&rcur[((cv.x >> 16) << QBITS) | q], 1);
        ebuf2[p] = cv;
    }
    __syncthreads();

    const int g  = tid & 15;
    const int lr = tid >> 4;
    const int row = grp * GROUP_ROWS + lr;
    const int jb = rstart[lr << QBITS];
    const int je = rstart[(lr + 1) << QBITS];
    float4 A0 = make_float4(0.f, 0.f, 0.f, 0.f);
    float4 A1 = make_float4(0.f, 0.f, 0.f, 0.f);
    float4 A2 = make_float4(0.f, 0.f, 0.f, 0.f);
    float4 A3 = make_float4(0.f, 0.f, 0.f, 0.f);
    int j = jb;
    for (; j + 4 <= je; j += 4) {
        int2 c0 = ebuf2[j];
        int2 c1 = ebuf2[j + 1];
        int2 c2 = ebuf2[j + 2];
        int2 c3 = ebuf2[j + 3];
        h4 s0 = *(const h4*)&support[(size_t)(c0.x & 0xFFFF) * OUT_DIM + g * 4];
        h4 s1 = *(const h4*)&support[(size_t)(c1.x & 0xFFFF) * OUT_DIM + g * 4];
        h4 s2 = *(const h4*)&support[(size_t)(c2.x & 0xFFFF) * OUT_DIM + g * 4];
        h4 s3 = *(const h4*)&support[(size_t)(c3.x & 0xFFFF) * OUT_DIM + g * 4];
        float v0 = __int_as_float(c0.y);
        float v1 = __int_as_float(c1.y);
        float v2 = __int_as_float(c2.y);
        float v3 = __int_as_float(c3.y);
        A0.x += v0 * (float)s0[0]; A0.y += v0 * (float)s0[1];
        A0.z += v0 * (float)s0[2]; A0.w += v0 * (float)s0[3];
        A1.x += v1 * (float)s1[0]; A1.y += v1 * (float)s1[1];
        A1.z += v1 * (float)s1[2]; A1.w += v1 * (float)s1[3];
        A2.x += v2 * (float)s2[0]; A2.y += v2 * (float)s2[1];
        A2.z += v2 * (float)s2[2]; A2.w += v2 * (float)s2[3];
        A3.x += v3 * (float)s3[0]; A3.y += v3 * (float)s3[1];
        A3.z += v3 * (float)s3[2]; A3.w += v3 * (float)s3[3];
    }
    for (; j < je; ++j) {
        int2 cv = ebuf2[j];
        float v = __int_as_float(cv.y);
        h4 sr = *(const h4*)&support[(size_t)(cv.x & 0xFFFF) * OUT_DIM + g * 4];
        A0.x += v * (float)sr[0]; A0.y += v * (float)sr[1];
        A0.z += v * (float)sr[2]; A0.w += v * (float)sr[3];
    }
    if (row < N_NODES) {
        float4 a;
        a.x = fmaxf(A0.x + A1.x + A2.x + A3.x, 0.f);
        a.y = fmaxf(A0.y + A1.y + A2.y + A3.y, 0.f);
        a.z = fmaxf(A0.z + A1.z + A2.z + A3.z, 0.f);
        a.w = fmaxf(A0.w + A1.w + A2.w + A3.w, 0.f);
        *(float4*)&out[(size_t)row * OUT_DIM + g * 4] = a;
    }
}

extern "C" void kernel_launch(void* const* d_in, const int* in_sizes, int n_in,
                              void* d_out, int out_size, void* d_ws, size_t ws_size,
                              hipStream_t stream) {
    const float* x    = (const float*)d_in[0];
    const int*   erow = (const int*)  d_in[1];
    const int*   ecol = (const int*)  d_in[2];
    const float* ev   = (const float*)d_in[3];
    const float* w    = (const float*)d_in[4];
    float* out = (float*)d_out;

    // workspace layout (16B-aligned), total ~14.0 MB
    char* ws = (char*)d_ws;
    _Float16* support = (_Float16*)ws;               //  6,400,000 B
    int*  gcursor = (int*)(ws + 6400000);            //      3,128 B
    int2* bucket  = (int2*)(ws + 6403200);           //  7,607,296 B

    hipMemsetAsync(gcursor, 0, sizeof(int) * N_GROUPS, stream);

    fused_gemm_fill<<<FILL_BLOCKS + N_GROUPS, 256, 0, stream>>>(
        x, w, erow, ecol, ev, support, gcursor, bucket);

    reduce_group<<<N_GROUPS, 1024, 0, stream>>>(gcursor, bucket, support, out);
}